// Round 1
// baseline (1758.022 us; speedup 1.0000x reference)
//
#include <hip/hip_runtime.h>

#define N_NODES 100000
#define E_EDGES 1600000
#define INC 128
#define HIDDEN 128
#define NCLS 10

// ---------------- degree / norm ----------------
__global__ void k_init_deg(float* __restrict__ deg) {
    int i = blockIdx.x * blockDim.x + threadIdx.x;
    if (i < N_NODES) deg[i] = 1.0f;   // self-loop
}

__global__ void k_count(const int* __restrict__ col, float* __restrict__ deg) {
    int e = blockIdx.x * blockDim.x + threadIdx.x;
    if (e < E_EDGES) atomicAdd(&deg[col[e]], 1.0f);
}

__global__ void k_rsqrt(float* __restrict__ deg) {
    int i = blockIdx.x * blockDim.x + threadIdx.x;
    if (i < N_NODES) deg[i] = rsqrtf(deg[i]);
}

// ---------------- GEMM1: h1 = x @ W1^T  (f32, LDS-tiled) ----------------
// block = 256 threads, 64 rows per block.
// W1 staged transposed in LDS (wt[k][j] = W1[j][k], padded to 132).
// Each thread: 2 rows x 4 consecutive output cols (float4 LDS reads).
__global__ __launch_bounds__(256) void k_gemm1(const float* __restrict__ x,
                                               const float* __restrict__ W1,
                                               float* __restrict__ h1) {
    __shared__ float wt[128][132];
    __shared__ float xs[16][128];
    int t = threadIdx.x;

    // load W1 transposed: 4096 float4 elements
    for (int idx = t; idx < 4096; idx += 256) {
        float4 v = ((const float4*)W1)[idx];
        int j  = idx >> 5;          // W1 row (= output col)
        int k4 = (idx & 31) << 2;   // k base
        wt[k4 + 0][j] = v.x;
        wt[k4 + 1][j] = v.y;
        wt[k4 + 2][j] = v.z;
        wt[k4 + 3][j] = v.w;
    }

    int row0 = blockIdx.x * 64;
    int jq = (t & 31) << 2;   // output col base (0..124)
    int rp = (t >> 5) << 1;   // row pair base within 16-row group

    for (int it = 0; it < 4; ++it) {
        int rbase = row0 + it * 16;
        __syncthreads();  // covers wt writes (it=0) and previous-iter xs reads
        // stage 16 rows of x (512 float4, 2 per thread)
        for (int l = t; l < 512; l += 256) {
            int rr = l >> 5;
            int cc = (l & 31) << 2;
            int gr = rbase + rr;
            float4 v = (gr < N_NODES) ? ((const float4*)x)[gr * 32 + (cc >> 2)]
                                      : make_float4(0.f, 0.f, 0.f, 0.f);
            *(float4*)&xs[rr][cc] = v;
        }
        __syncthreads();

        float4 acc0 = {0.f, 0.f, 0.f, 0.f};
        float4 acc1 = {0.f, 0.f, 0.f, 0.f};
        #pragma unroll 8
        for (int k = 0; k < 128; ++k) {
            float4 wv = *(const float4*)&wt[k][jq];
            float xv0 = xs[rp][k];
            float xv1 = xs[rp + 1][k];
            acc0.x += xv0 * wv.x; acc0.y += xv0 * wv.y;
            acc0.z += xv0 * wv.z; acc0.w += xv0 * wv.w;
            acc1.x += xv1 * wv.x; acc1.y += xv1 * wv.y;
            acc1.z += xv1 * wv.z; acc1.w += xv1 * wv.w;
        }
        int r0 = rbase + rp;
        int r1 = r0 + 1;
        if (r0 < N_NODES) *(float4*)&h1[r0 * 128 + jq] = acc0;
        if (r1 < N_NODES) *(float4*)&h1[r1 * 128 + jq] = acc1;
    }
}

// ---------------- layer-1 aggregation ----------------
__global__ void k_agg_init128(const float* __restrict__ h1, const float* __restrict__ dis,
                              const float* __restrict__ b1, float* __restrict__ out1) {
    int tid = blockIdx.x * blockDim.x + threadIdx.x;   // < N*128 = 12.8M
    int i = tid >> 7;
    int f = tid & 127;
    if (i < N_NODES) {
        float d = dis[i];
        out1[tid] = b1[f] + d * d * h1[tid];
    }
}

__global__ void k_agg_edge128(const float* __restrict__ h1, const float* __restrict__ dis,
                              const int* __restrict__ ei, float* __restrict__ out1) {
    unsigned tid = blockIdx.x * 256u + threadIdx.x;    // E*128 = 204.8M threads
    unsigned e = tid >> 7;
    int f = tid & 127;
    if (e < E_EDGES) {
        int r = ei[e];
        int c = ei[E_EDGES + e];
        float w = dis[r] * dis[c];
        atomicAdd(&out1[c * 128 + f], w * h1[r * 128 + f]);
    }
}

// ---------------- GEMM2: h2 = out1 @ W2^T  (wave per row) ----------------
__global__ __launch_bounds__(256) void k_gemm2(const float* __restrict__ out1,
                                               const float* __restrict__ W2,
                                               float* __restrict__ h2) {
    int wid  = (blockIdx.x * 256 + threadIdx.x) >> 6;   // row
    int lane = threadIdx.x & 63;
    if (wid >= N_NODES) return;
    float v0 = out1[wid * 128 + lane];
    float v1 = out1[wid * 128 + 64 + lane];
    float res = 0.f;
    #pragma unroll
    for (int j = 0; j < NCLS; ++j) {
        float p = v0 * W2[j * 128 + lane] + v1 * W2[j * 128 + 64 + lane];
        #pragma unroll
        for (int s = 32; s; s >>= 1) p += __shfl_xor(p, s);
        if (lane == j) res = p;
    }
    if (lane < NCLS) h2[wid * NCLS + lane] = res;
}

// ---------------- layer-2 aggregation ----------------
__global__ void k_agg_init10(const float* __restrict__ h2, const float* __restrict__ dis,
                             const float* __restrict__ b2, float* __restrict__ out) {
    int tid = blockIdx.x * blockDim.x + threadIdx.x;
    if (tid < N_NODES * NCLS) {
        int i = tid / NCLS;
        int j = tid - i * NCLS;
        float d = dis[i];
        out[tid] = b2[j] + d * d * h2[tid];
    }
}

__global__ void k_agg_edge10(const float* __restrict__ h2, const float* __restrict__ dis,
                             const int* __restrict__ ei, float* __restrict__ out) {
    int e = blockIdx.x * blockDim.x + threadIdx.x;
    if (e < E_EDGES) {
        int r = ei[e];
        int c = ei[E_EDGES + e];
        float w = dis[r] * dis[c];
        #pragma unroll
        for (int j = 0; j < NCLS; ++j)
            atomicAdd(&out[c * NCLS + j], w * h2[r * NCLS + j]);
    }
}

extern "C" void kernel_launch(void* const* d_in, const int* in_sizes, int n_in,
                              void* d_out, int out_size, void* d_ws, size_t ws_size,
                              hipStream_t stream) {
    const float* x  = (const float*)d_in[0];
    const int*   ei = (const int*)d_in[1];   // [2, E] int32
    const float* W1 = (const float*)d_in[2];
    const float* b1 = (const float*)d_in[3];
    const float* W2 = (const float*)d_in[4];
    const float* b2 = (const float*)d_in[5];
    float* out = (float*)d_out;

    char* ws = (char*)d_ws;
    float* dis  = (float*)ws;                               // N floats
    float* h1   = (float*)(ws + (1 << 20));                 // N*128 floats
    float* out1 = (float*)(ws + (1 << 20) + 52428800);      // N*128 floats
    float* h2   = h1;                                       // h1 dead after edge128

    k_init_deg<<<(N_NODES + 255) / 256, 256, 0, stream>>>(dis);
    k_count<<<(E_EDGES + 255) / 256, 256, 0, stream>>>(ei + E_EDGES, dis);
    k_rsqrt<<<(N_NODES + 255) / 256, 256, 0, stream>>>(dis);

    // layer 1
    k_gemm1<<<(N_NODES + 63) / 64, 256, 0, stream>>>(x, W1, h1);
    k_agg_init128<<<(N_NODES * 128) / 256, 256, 0, stream>>>(h1, dis, b1, out1);
    k_agg_edge128<<<(E_EDGES * 128) / 256, 256, 0, stream>>>(h1, dis, ei, out1);

    // layer 2
    k_gemm2<<<(N_NODES + 3) / 4, 256, 0, stream>>>(out1, W2, h2);
    k_agg_init10<<<(N_NODES * NCLS + 255) / 256, 256, 0, stream>>>(h2, dis, b2, out);
    k_agg_edge10<<<(E_EDGES + 255) / 256, 256, 0, stream>>>(h2, dis, ei, out);
}

// Round 2
// 510.560 us; speedup vs baseline: 3.4433x; 3.4433x over previous
//
#include <hip/hip_runtime.h>

#define N_NODES 100000
#define E_EDGES 1600000
#define NCLS 10

// ---------------- zero / degree / norm ----------------
__global__ void k_zero2(int* __restrict__ a, int* __restrict__ b) {
    int i = blockIdx.x * blockDim.x + threadIdx.x;
    if (i < N_NODES) { a[i] = 0; b[i] = 0; }
}

__global__ void k_count(const int* __restrict__ col, int* __restrict__ degi) {
    int e = blockIdx.x * blockDim.x + threadIdx.x;
    if (e < E_EDGES) atomicAdd(&degi[col[e]], 1);
}

__global__ void k_dis(const int* __restrict__ degi, float* __restrict__ dis) {
    int i = blockIdx.x * blockDim.x + threadIdx.x;
    if (i < N_NODES) dis[i] = rsqrtf((float)(degi[i] + 1));  // +1 self-loop
}

// ---------------- prefix scan of degi -> offs (deterministic, 3 kernels) ---
// N = 100000 = 98 chunks of 1024 (256 thr x int4)
__global__ __launch_bounds__(256) void k_scan_block(const int* __restrict__ degi,
                                                    int* __restrict__ bsum) {
    __shared__ int s[256];
    int t = threadIdx.x;
    int idx4 = blockIdx.x * 256 + t;
    int4 v = (idx4 < 25000) ? ((const int4*)degi)[idx4] : make_int4(0, 0, 0, 0);
    s[t] = v.x + v.y + v.z + v.w;
    __syncthreads();
    for (int st = 128; st; st >>= 1) {
        if (t < st) s[t] += s[t + st];
        __syncthreads();
    }
    if (t == 0) bsum[blockIdx.x] = s[0];
}

__global__ __launch_bounds__(128) void k_scan_mid(const int* __restrict__ bsum,
                                                  int* __restrict__ bbase) {
    __shared__ int s[128];
    int t = threadIdx.x;
    int v = (t < 98) ? bsum[t] : 0;
    s[t] = v;
    __syncthreads();
    for (int st = 1; st < 128; st <<= 1) {
        int tmp = (t >= st) ? s[t - st] : 0;
        __syncthreads();
        s[t] += tmp;
        __syncthreads();
    }
    if (t < 98) bbase[t] = s[t] - v;  // exclusive
}

__global__ __launch_bounds__(256) void k_scan_write(const int* __restrict__ degi,
                                                    const int* __restrict__ bbase,
                                                    int* __restrict__ offs) {
    __shared__ int s[256];
    int t = threadIdx.x;
    int idx4 = blockIdx.x * 256 + t;
    int4 v = (idx4 < 25000) ? ((const int4*)degi)[idx4] : make_int4(0, 0, 0, 0);
    int local = v.x + v.y + v.z + v.w;
    s[t] = local;
    __syncthreads();
    for (int st = 1; st < 256; st <<= 1) {
        int tmp = (t >= st) ? s[t - st] : 0;
        __syncthreads();
        s[t] += tmp;
        __syncthreads();
    }
    if (idx4 < 25000) {
        int base = bbase[blockIdx.x] + s[t] - local;  // exclusive
        int4 o;
        o.x = base;
        o.y = o.x + v.x;
        o.z = o.y + v.y;
        o.w = o.z + v.z;
        ((int4*)offs)[idx4] = o;
    }
}

// ---------------- CSR fill ----------------
__global__ void k_csr_fill(const int* __restrict__ ei, const int* __restrict__ offs,
                           int* __restrict__ cur, int* __restrict__ csr) {
    int e = blockIdx.x * blockDim.x + threadIdx.x;
    if (e < E_EDGES) {
        int r = ei[e];
        int c = ei[E_EDGES + e];
        int pos = offs[c] + atomicAdd(&cur[c], 1);
        csr[pos] = r;
    }
}

// ---------------- GEMM1: h1 = x @ W1^T  (f32, LDS-tiled) ----------------
__global__ __launch_bounds__(256) void k_gemm1(const float* __restrict__ x,
                                               const float* __restrict__ W1,
                                               float* __restrict__ h1) {
    __shared__ float wt[128][132];
    __shared__ float xs[16][128];
    int t = threadIdx.x;

    for (int idx = t; idx < 4096; idx += 256) {
        float4 v = ((const float4*)W1)[idx];
        int j  = idx >> 5;
        int k4 = (idx & 31) << 2;
        wt[k4 + 0][j] = v.x;
        wt[k4 + 1][j] = v.y;
        wt[k4 + 2][j] = v.z;
        wt[k4 + 3][j] = v.w;
    }

    int row0 = blockIdx.x * 64;
    int jq = (t & 31) << 2;
    int rp = (t >> 5) << 1;

    for (int it = 0; it < 4; ++it) {
        int rbase = row0 + it * 16;
        __syncthreads();
        for (int l = t; l < 512; l += 256) {
            int rr = l >> 5;
            int cc = (l & 31) << 2;
            int gr = rbase + rr;
            float4 v = (gr < N_NODES) ? ((const float4*)x)[gr * 32 + (cc >> 2)]
                                      : make_float4(0.f, 0.f, 0.f, 0.f);
            *(float4*)&xs[rr][cc] = v;
        }
        __syncthreads();

        float4 acc0 = {0.f, 0.f, 0.f, 0.f};
        float4 acc1 = {0.f, 0.f, 0.f, 0.f};
        #pragma unroll 8
        for (int k = 0; k < 128; ++k) {
            float4 wv = *(const float4*)&wt[k][jq];
            float xv0 = xs[rp][k];
            float xv1 = xs[rp + 1][k];
            acc0.x += xv0 * wv.x; acc0.y += xv0 * wv.y;
            acc0.z += xv0 * wv.z; acc0.w += xv0 * wv.w;
            acc1.x += xv1 * wv.x; acc1.y += xv1 * wv.y;
            acc1.z += xv1 * wv.z; acc1.w += xv1 * wv.w;
        }
        int r0 = rbase + rp;
        int r1 = r0 + 1;
        if (r0 < N_NODES) *(float4*)&h1[r0 * 128 + jq] = acc0;
        if (r1 < N_NODES) *(float4*)&h1[r1 * 128 + jq] = acc1;
    }
}

// ------- agg1 (gather) + fused GEMM2: h2[c,:] = (Agg(h1)+b1)[c,:] @ W2^T ----
// one wave per destination node; lanes hold feats (lane, lane+64)
__global__ __launch_bounds__(256) void k_agg1_gemm2(const float* __restrict__ h1,
                                                    const float* __restrict__ dis,
                                                    const int* __restrict__ csr,
                                                    const int* __restrict__ offs,
                                                    const int* __restrict__ degi,
                                                    const float* __restrict__ b1,
                                                    const float* __restrict__ W2,
                                                    float* __restrict__ h2) {
    int c    = blockIdx.x * 4 + (threadIdx.x >> 6);
    int lane = threadIdx.x & 63;
    if (c >= N_NODES) return;

    float dc = dis[c];
    float acc0 = dc * h1[c * 128 + lane];        // self-loop (x dc later)
    float acc1 = dc * h1[c * 128 + 64 + lane];

    int start = offs[c];
    int deg   = degi[c];
    for (int j = 0; j < deg; ++j) {
        int r = csr[start + j];
        float w = dis[r];
        acc0 += w * h1[r * 128 + lane];
        acc1 += w * h1[r * 128 + 64 + lane];
    }

    float o0 = b1[lane]      + dc * acc0;   // out1 row in registers
    float o1 = b1[lane + 64] + dc * acc1;

    float res = 0.f;
    #pragma unroll
    for (int j = 0; j < NCLS; ++j) {
        float p = o0 * W2[j * 128 + lane] + o1 * W2[j * 128 + 64 + lane];
        #pragma unroll
        for (int s = 32; s; s >>= 1) p += __shfl_xor(p, s);
        if (lane == j) res = p;
    }
    if (lane < NCLS) h2[c * NCLS + lane] = res;
}

// ---------------- agg2 (gather, 16-lane group per dest) ----------------
__global__ __launch_bounds__(256) void k_agg2(const float* __restrict__ h2,
                                              const float* __restrict__ dis,
                                              const int* __restrict__ csr,
                                              const int* __restrict__ offs,
                                              const int* __restrict__ degi,
                                              const float* __restrict__ b2,
                                              float* __restrict__ out) {
    int c = blockIdx.x * 16 + (threadIdx.x >> 4);
    int j = threadIdx.x & 15;
    if (c >= N_NODES) return;

    float dc = dis[c];
    float acc = 0.f;
    if (j < NCLS) acc = dc * h2[c * NCLS + j];

    int start = offs[c];
    int deg   = degi[c];
    for (int k = 0; k < deg; ++k) {
        int r = csr[start + k];
        if (j < NCLS) acc += dis[r] * h2[r * NCLS + j];
    }
    if (j < NCLS) out[c * NCLS + j] = b2[j] + dc * acc;
}

extern "C" void kernel_launch(void* const* d_in, const int* in_sizes, int n_in,
                              void* d_out, int out_size, void* d_ws, size_t ws_size,
                              hipStream_t stream) {
    const float* x  = (const float*)d_in[0];
    const int*   ei = (const int*)d_in[1];   // [2, E] int32
    const float* W1 = (const float*)d_in[2];
    const float* b1 = (const float*)d_in[3];
    const float* W2 = (const float*)d_in[4];
    const float* b2 = (const float*)d_in[5];
    float* out = (float*)d_out;

    char* ws = (char*)d_ws;
    int*   degi  = (int*)(ws + 0);
    int*   cur   = (int*)(ws + (1 << 20));
    int*   offs  = (int*)(ws + (2 << 20));
    float* dis   = (float*)(ws + (3 << 20));
    int*   bsum  = (int*)(ws + (3 << 20) + 524288);
    int*   bbase = (int*)(ws + (3 << 20) + 655360);
    int*   csr   = (int*)(ws + (4 << 20));      // 6.4 MB
    float* h2    = (float*)(ws + (12 << 20));   // 4 MB
    float* h1    = (float*)(ws + (16 << 20));   // 51.2 MB

    k_zero2<<<(N_NODES + 255) / 256, 256, 0, stream>>>(degi, cur);
    k_count<<<(E_EDGES + 255) / 256, 256, 0, stream>>>(ei + E_EDGES, degi);
    k_dis<<<(N_NODES + 255) / 256, 256, 0, stream>>>(degi, dis);

    k_scan_block<<<98, 256, 0, stream>>>(degi, bsum);
    k_scan_mid<<<1, 128, 0, stream>>>(bsum, bbase);
    k_scan_write<<<98, 256, 0, stream>>>(degi, bbase, offs);
    k_csr_fill<<<(E_EDGES + 255) / 256, 256, 0, stream>>>(ei, offs, cur, csr);

    k_gemm1<<<(N_NODES + 63) / 64, 256, 0, stream>>>(x, W1, h1);

    k_agg1_gemm2<<<(N_NODES + 3) / 4, 256, 0, stream>>>(h1, dis, csr, offs, degi,
                                                        b1, W2, h2);
    k_agg2<<<(N_NODES + 15) / 16, 256, 0, stream>>>(h2, dis, csr, offs, degi, b2, out);
}

// Round 3
// 390.184 us; speedup vs baseline: 4.5056x; 1.3085x over previous
//
#include <hip/hip_runtime.h>

#define N_NODES 100000
#define E_EDGES 1600000
#define NCLS 10

// ---------------- zero / degree / norm ----------------
__global__ void k_zero2(int* __restrict__ a, int* __restrict__ b) {
    int i = blockIdx.x * blockDim.x + threadIdx.x;
    if (i < N_NODES) { a[i] = 0; b[i] = 0; }
}

__global__ void k_count(const int* __restrict__ col, int* __restrict__ degi) {
    int e = blockIdx.x * blockDim.x + threadIdx.x;
    if (e < E_EDGES) atomicAdd(&degi[col[e]], 1);
}

__global__ void k_dis(const int* __restrict__ degi, float* __restrict__ dis) {
    int i = blockIdx.x * blockDim.x + threadIdx.x;
    if (i < N_NODES) dis[i] = rsqrtf((float)(degi[i] + 1));  // +1 self-loop
}

// ---------------- prefix scan of degi -> offs ----------------
__global__ __launch_bounds__(256) void k_scan_block(const int* __restrict__ degi,
                                                    int* __restrict__ bsum) {
    __shared__ int s[256];
    int t = threadIdx.x;
    int idx4 = blockIdx.x * 256 + t;
    int4 v = (idx4 < 25000) ? ((const int4*)degi)[idx4] : make_int4(0, 0, 0, 0);
    s[t] = v.x + v.y + v.z + v.w;
    __syncthreads();
    for (int st = 128; st; st >>= 1) {
        if (t < st) s[t] += s[t + st];
        __syncthreads();
    }
    if (t == 0) bsum[blockIdx.x] = s[0];
}

__global__ __launch_bounds__(128) void k_scan_mid(const int* __restrict__ bsum,
                                                  int* __restrict__ bbase) {
    __shared__ int s[128];
    int t = threadIdx.x;
    int v = (t < 98) ? bsum[t] : 0;
    s[t] = v;
    __syncthreads();
    for (int st = 1; st < 128; st <<= 1) {
        int tmp = (t >= st) ? s[t - st] : 0;
        __syncthreads();
        s[t] += tmp;
        __syncthreads();
    }
    if (t < 98) bbase[t] = s[t] - v;  // exclusive
}

__global__ __launch_bounds__(256) void k_scan_write(const int* __restrict__ degi,
                                                    const int* __restrict__ bbase,
                                                    int* __restrict__ offs) {
    __shared__ int s[256];
    int t = threadIdx.x;
    int idx4 = blockIdx.x * 256 + t;
    int4 v = (idx4 < 25000) ? ((const int4*)degi)[idx4] : make_int4(0, 0, 0, 0);
    int local = v.x + v.y + v.z + v.w;
    s[t] = local;
    __syncthreads();
    for (int st = 1; st < 256; st <<= 1) {
        int tmp = (t >= st) ? s[t - st] : 0;
        __syncthreads();
        s[t] += tmp;
        __syncthreads();
    }
    if (idx4 < 25000) {
        int base = bbase[blockIdx.x] + s[t] - local;  // exclusive
        int4 o;
        o.x = base;
        o.y = o.x + v.x;
        o.z = o.y + v.y;
        o.w = o.z + v.z;
        ((int4*)offs)[idx4] = o;
    }
}

// ---------------- CSR fill ----------------
__global__ void k_csr_fill(const int* __restrict__ ei, const int* __restrict__ offs,
                           int* __restrict__ cur, int* __restrict__ csr) {
    int e = blockIdx.x * blockDim.x + threadIdx.x;
    if (e < E_EDGES) {
        int r = ei[e];
        int c = ei[E_EDGES + e];
        int pos = offs[c] + atomicAdd(&cur[c], 1);
        csr[pos] = r;
    }
}

// ---------------- W12 = W2 @ W1 ([10,128]), c1 = W2 @ b1 ----------------
__global__ __launch_bounds__(256) void k_w12(const float* __restrict__ W1,
                                             const float* __restrict__ W2,
                                             const float* __restrict__ b1,
                                             float* __restrict__ W12,
                                             float* __restrict__ c1) {
    __shared__ float w1s[128][128];   // w1s[m][k]
    int t = threadIdx.x;
    for (int i = t; i < 4096; i += 256) {
        float4 v = ((const float4*)W1)[i];
        int m = i >> 5;
        int k = (i & 31) << 2;
        *(float4*)&w1s[m][k] = v;
    }
    __syncthreads();

    int j0 = t >> 7;          // 0 or 1
    int k  = t & 127;
    #pragma unroll
    for (int i = 0; i < 5; ++i) {
        int j = j0 * 5 + i;
        float acc = 0.f;
        for (int m = 0; m < 128; ++m)
            acc += W2[j * 128 + m] * w1s[m][k];
        W12[j * 128 + k] = acc;
    }
    if (t < 16) {
        float acc = 0.f;
        if (t < NCLS)
            for (int m = 0; m < 128; ++m) acc += W2[t * 128 + m] * b1[m];
        c1[t] = (t < NCLS) ? acc : 0.f;
    }
}

// ---------------- g1 = x @ W12^T, padded [N][16], dis in slot 10 ----------
__global__ __launch_bounds__(256) void k_g1(const float* __restrict__ x,
                                            const float* __restrict__ dis,
                                            const float* __restrict__ W12,
                                            float* __restrict__ g1p) {
    __shared__ float ws[1280];
    int t = threadIdx.x;
    for (int i = t; i < 1280; i += 256) ws[i] = W12[i];
    __syncthreads();

    int row  = blockIdx.x * 4 + (t >> 6);
    int lane = t & 63;
    if (row >= N_NODES) return;

    float v0 = x[row * 128 + lane];
    float v1 = x[row * 128 + 64 + lane];
    float res = 0.f;
    #pragma unroll
    for (int j = 0; j < NCLS; ++j) {
        float p = v0 * ws[j * 128 + lane] + v1 * ws[j * 128 + 64 + lane];
        #pragma unroll
        for (int s = 32; s; s >>= 1) p += __shfl_xor(p, s);
        if (lane == j) res = p;
    }
    if (lane < 16) {
        float o = (lane < NCLS) ? res : (lane == 10 ? dis[row] : 0.f);
        g1p[row * 16 + lane] = o;
    }
}

// ------- agg A: h2p = S*g1 + c1 (padded rows, dis in slot 10) -------------
__global__ __launch_bounds__(256) void k_agg_a(const float* __restrict__ g1p,
                                               const int* __restrict__ csr,
                                               const int* __restrict__ offs,
                                               const int* __restrict__ degi,
                                               const float* __restrict__ c1,
                                               float* __restrict__ h2p) {
    int c    = blockIdx.x * 16 + (threadIdx.x >> 4);
    int lane = threadIdx.x & 15;
    if (c >= N_NODES) return;

    float vs = g1p[c * 16 + lane];
    float dc = __shfl(vs, 10, 16);
    float acc = dc * vs;

    int start = offs[c];
    int deg   = degi[c];
    for (int k = 0; k < deg; ++k) {
        int r = csr[start + k];
        float vr = g1p[r * 16 + lane];
        acc += __shfl(vr, 10, 16) * vr;
    }
    float o = (lane < NCLS) ? dc * acc + c1[lane] : (lane == 10 ? dc : 0.f);
    h2p[c * 16 + lane] = o;
}

// ------- agg B: out = S*h2 + b2 (compact N x 10 output) -------------------
__global__ __launch_bounds__(256) void k_agg_b(const float* __restrict__ h2p,
                                               const int* __restrict__ csr,
                                               const int* __restrict__ offs,
                                               const int* __restrict__ degi,
                                               const float* __restrict__ b2,
                                               float* __restrict__ out) {
    int c    = blockIdx.x * 16 + (threadIdx.x >> 4);
    int lane = threadIdx.x & 15;
    if (c >= N_NODES) return;

    float vs = h2p[c * 16 + lane];
    float dc = __shfl(vs, 10, 16);
    float acc = dc * vs;

    int start = offs[c];
    int deg   = degi[c];
    for (int k = 0; k < deg; ++k) {
        int r = csr[start + k];
        float vr = h2p[r * 16 + lane];
        acc += __shfl(vr, 10, 16) * vr;
    }
    if (lane < NCLS) out[c * NCLS + lane] = b2[lane] + dc * acc;
}

extern "C" void kernel_launch(void* const* d_in, const int* in_sizes, int n_in,
                              void* d_out, int out_size, void* d_ws, size_t ws_size,
                              hipStream_t stream) {
    const float* x  = (const float*)d_in[0];
    const int*   ei = (const int*)d_in[1];   // [2, E] int32
    const float* W1 = (const float*)d_in[2];
    const float* b1 = (const float*)d_in[3];
    const float* W2 = (const float*)d_in[4];
    const float* b2 = (const float*)d_in[5];
    float* out = (float*)d_out;

    char* ws = (char*)d_ws;
    int*   degi  = (int*)(ws + 0);               // 400 KB
    int*   cur   = (int*)(ws + (1 << 20));
    int*   offs  = (int*)(ws + (2 << 20));
    float* dis   = (float*)(ws + (3 << 20));
    int*   bsum  = (int*)(ws + (3 << 20) + 524288);
    int*   bbase = (int*)(ws + (3 << 20) + 655360);
    float* W12   = (float*)(ws + (3 << 20) + 786432);   // 5 KB
    float* c1    = (float*)(ws + (3 << 20) + 917504);   // 64 B
    int*   csr   = (int*)(ws + (4 << 20));      // 6.4 MB
    float* g1p   = (float*)(ws + (12 << 20));   // 6.4 MB
    float* h2p   = (float*)(ws + (20 << 20));   // 6.4 MB

    k_zero2<<<(N_NODES + 255) / 256, 256, 0, stream>>>(degi, cur);
    k_count<<<(E_EDGES + 255) / 256, 256, 0, stream>>>(ei + E_EDGES, degi);
    k_dis<<<(N_NODES + 255) / 256, 256, 0, stream>>>(degi, dis);

    k_scan_block<<<98, 256, 0, stream>>>(degi, bsum);
    k_scan_mid<<<1, 128, 0, stream>>>(bsum, bbase);
    k_scan_write<<<98, 256, 0, stream>>>(degi, bbase, offs);
    k_csr_fill<<<(E_EDGES + 255) / 256, 256, 0, stream>>>(ei, offs, cur, csr);

    k_w12<<<1, 256, 0, stream>>>(W1, W2, b1, W12, c1);
    k_g1<<<(N_NODES + 3) / 4, 256, 0, stream>>>(x, dis, W12, g1p);

    k_agg_a<<<(N_NODES + 15) / 16, 256, 0, stream>>>(g1p, csr, offs, degi, c1, h2p);
    k_agg_b<<<(N_NODES + 15) / 16, 256, 0, stream>>>(h2p, csr, offs, degi, b2, out);
}

// Round 4
// 256.975 us; speedup vs baseline: 6.8412x; 1.5184x over previous
//
#include <hip/hip_runtime.h>

#define N_NODES 100000
#define E_EDGES 1600000
#define NCLS 10

#define BW 256                       // bucket width in nodes
#define NB 391                       // ceil(N_NODES / BW)
#define EPB 8192                     // edges per binning block
#define NBLK_BIN 196                 // ceil(E_EDGES / EPB)

// ---------------- bucket histogram ----------------
__global__ __launch_bounds__(256) void k_hist(const int* __restrict__ col,
                                              int* __restrict__ bucketCount) {
    __shared__ int h[NB];
    int t = threadIdx.x;
    for (int i = t; i < NB; i += 256) h[i] = 0;
    __syncthreads();
    int base = blockIdx.x * EPB;
    int end  = min(base + EPB, E_EDGES);
    for (int e = base + t; e < end; e += 256)
        atomicAdd(&h[col[e] >> 8], 1);
    __syncthreads();
    for (int i = t; i < NB; i += 256)
        if (h[i]) atomicAdd(&bucketCount[i], h[i]);
}

// ---------------- scan buckets -> bases + cursors ----------------
__global__ __launch_bounds__(512) void k_scan_buckets(const int* __restrict__ bucketCount,
                                                      int* __restrict__ bucketBase,
                                                      int* __restrict__ cursors) {
    __shared__ int s[512];
    int t = threadIdx.x;
    int v = (t < NB) ? bucketCount[t] : 0;
    s[t] = v;
    __syncthreads();
    for (int st = 1; st < 512; st <<= 1) {
        int tmp = (t >= st) ? s[t - st] : 0;
        __syncthreads();
        s[t] += tmp;
        __syncthreads();
    }
    if (t < NB) {
        int b = s[t] - v;   // exclusive
        bucketBase[t] = b;
        cursors[t] = b;
    }
    if (t == NB - 1) bucketBase[NB] = s[t];   // = E_EDGES
}

// ---------------- bin edges into bucketed packed array ----------------
__global__ __launch_bounds__(256) void k_bin(const int* __restrict__ ei,
                                             int* __restrict__ cursors,
                                             unsigned* __restrict__ binned) {
    __shared__ int h[NB];
    __shared__ int chunk[NB];
    int t = threadIdx.x;
    for (int i = t; i < NB; i += 256) h[i] = 0;
    __syncthreads();
    int base = blockIdx.x * EPB;
    int end  = min(base + EPB, E_EDGES);
    const int* col = ei + E_EDGES;
    for (int e = base + t; e < end; e += 256)
        atomicAdd(&h[col[e] >> 8], 1);
    __syncthreads();
    for (int i = t; i < NB; i += 256) {
        int n = h[i];
        chunk[i] = n ? atomicAdd(&cursors[i], n) : 0;
        h[i] = 0;    // reuse as local cursor
    }
    __syncthreads();
    for (int e = base + t; e < end; e += 256) {
        int c = col[e];
        int r = ei[e];
        int k = c >> 8;
        int slot = chunk[k] + atomicAdd(&h[k], 1);
        binned[slot] = ((unsigned)r << 8) | (unsigned)(c & 255);
    }
}

// ---------------- per-bucket: degrees, offs, dis, csr fill ----------------
__global__ __launch_bounds__(256) void k_build(const unsigned* __restrict__ binned,
                                               const int* __restrict__ bucketBase,
                                               int* __restrict__ degi,
                                               int* __restrict__ offs,
                                               float* __restrict__ dis,
                                               int* __restrict__ csr) {
    __shared__ int cnt[BW];
    __shared__ int sc[BW];
    __shared__ int eoff[BW];
    __shared__ int cur[BW];
    int k = blockIdx.x;
    int t = threadIdx.x;
    cnt[t] = 0;
    __syncthreads();
    int s0 = bucketBase[k], s1 = bucketBase[k + 1];
    for (int i = s0 + t; i < s1; i += 256)
        atomicAdd(&cnt[binned[i] & 255], 1);
    __syncthreads();
    int v = cnt[t];
    sc[t] = v;
    __syncthreads();
    for (int st = 1; st < 256; st <<= 1) {
        int tmp = (t >= st) ? sc[t - st] : 0;
        __syncthreads();
        sc[t] += tmp;
        __syncthreads();
    }
    eoff[t] = sc[t] - v;   // exclusive
    cur[t] = 0;
    int node = k * BW + t;
    if (node < N_NODES) {
        degi[node] = v;
        offs[node] = s0 + eoff[t];
        dis[node]  = rsqrtf((float)(v + 1));
    }
    __syncthreads();
    for (int i = s0 + t; i < s1; i += 256) {
        unsigned p = binned[i];
        int lc = p & 255;
        int r  = p >> 8;
        int pos = s0 + eoff[lc] + atomicAdd(&cur[lc], 1);
        csr[pos] = r;
    }
}

// ---------------- W12 = W2 @ W1 ([10,128]), c1 = W2 @ b1 ----------------
__global__ __launch_bounds__(256) void k_w12(const float* __restrict__ W1,
                                             const float* __restrict__ W2,
                                             const float* __restrict__ b1,
                                             float* __restrict__ W12,
                                             float* __restrict__ c1) {
    __shared__ float w1s[128][128];
    int t = threadIdx.x;
    for (int i = t; i < 4096; i += 256) {
        float4 v = ((const float4*)W1)[i];
        int m = i >> 5;
        int kk = (i & 31) << 2;
        *(float4*)&w1s[m][kk] = v;
    }
    __syncthreads();

    int j0 = t >> 7;
    int kk = t & 127;
    #pragma unroll
    for (int i = 0; i < 5; ++i) {
        int j = j0 * 5 + i;
        float acc = 0.f;
        for (int m = 0; m < 128; ++m)
            acc += W2[j * 128 + m] * w1s[m][kk];
        W12[j * 128 + kk] = acc;
    }
    if (t < 16) {
        float acc = 0.f;
        if (t < NCLS)
            for (int m = 0; m < 128; ++m) acc += W2[t * 128 + m] * b1[m];
        c1[t] = (t < NCLS) ? acc : 0.f;
    }
}

// ---------------- g1 = x @ W12^T, padded [N][16], dis in slot 10 ----------
__global__ __launch_bounds__(256) void k_g1(const float* __restrict__ x,
                                            const float* __restrict__ dis,
                                            const float* __restrict__ W12,
                                            float* __restrict__ g1p) {
    __shared__ float ws[1280];
    int t = threadIdx.x;
    for (int i = t; i < 1280; i += 256) ws[i] = W12[i];
    __syncthreads();

    int row  = blockIdx.x * 4 + (t >> 6);
    int lane = t & 63;
    if (row >= N_NODES) return;

    float v0 = x[row * 128 + lane];
    float v1 = x[row * 128 + 64 + lane];
    float res = 0.f;
    #pragma unroll
    for (int j = 0; j < NCLS; ++j) {
        float p = v0 * ws[j * 128 + lane] + v1 * ws[j * 128 + 64 + lane];
        #pragma unroll
        for (int s = 32; s; s >>= 1) p += __shfl_xor(p, s);
        if (lane == j) res = p;
    }
    if (lane < 16) {
        float o = (lane < NCLS) ? res : (lane == 10 ? dis[row] : 0.f);
        g1p[row * 16 + lane] = o;
    }
}

// ------- agg A: h2p = S*g1 + c1 (padded rows, dis in slot 10) -------------
__global__ __launch_bounds__(256) void k_agg_a(const float* __restrict__ g1p,
                                               const int* __restrict__ csr,
                                               const int* __restrict__ offs,
                                               const int* __restrict__ degi,
                                               const float* __restrict__ c1,
                                               float* __restrict__ h2p) {
    int c    = blockIdx.x * 16 + (threadIdx.x >> 4);
    int lane = threadIdx.x & 15;
    if (c >= N_NODES) return;

    float vs = g1p[c * 16 + lane];
    float dc = __shfl(vs, 10, 16);
    float acc = dc * vs;

    int start = offs[c];
    int deg   = degi[c];
    for (int k = 0; k < deg; ++k) {
        int r = csr[start + k];
        float vr = g1p[r * 16 + lane];
        acc += __shfl(vr, 10, 16) * vr;
    }
    float o = (lane < NCLS) ? dc * acc + c1[lane] : (lane == 10 ? dc : 0.f);
    h2p[c * 16 + lane] = o;
}

// ------- agg B: out = S*h2 + b2 (compact N x 10 output) -------------------
__global__ __launch_bounds__(256) void k_agg_b(const float* __restrict__ h2p,
                                               const int* __restrict__ csr,
                                               const int* __restrict__ offs,
                                               const int* __restrict__ degi,
                                               const float* __restrict__ b2,
                                               float* __restrict__ out) {
    int c    = blockIdx.x * 16 + (threadIdx.x >> 4);
    int lane = threadIdx.x & 15;
    if (c >= N_NODES) return;

    float vs = h2p[c * 16 + lane];
    float dc = __shfl(vs, 10, 16);
    float acc = dc * vs;

    int start = offs[c];
    int deg   = degi[c];
    for (int k = 0; k < deg; ++k) {
        int r = csr[start + k];
        float vr = h2p[r * 16 + lane];
        acc += __shfl(vr, 10, 16) * vr;
    }
    if (lane < NCLS) out[c * NCLS + lane] = b2[lane] + dc * acc;
}

extern "C" void kernel_launch(void* const* d_in, const int* in_sizes, int n_in,
                              void* d_out, int out_size, void* d_ws, size_t ws_size,
                              hipStream_t stream) {
    const float* x  = (const float*)d_in[0];
    const int*   ei = (const int*)d_in[1];   // [2, E] int32
    const float* W1 = (const float*)d_in[2];
    const float* b1 = (const float*)d_in[3];
    const float* W2 = (const float*)d_in[4];
    const float* b2 = (const float*)d_in[5];
    float* out = (float*)d_out;

    char* ws = (char*)d_ws;
    int*      bucketCount = (int*)(ws + 0);                 // NB ints
    int*      bucketBase  = (int*)(ws + 4096);              // NB+1 ints
    int*      cursors     = (int*)(ws + 8192);              // NB ints
    float*    W12         = (float*)(ws + 16384);           // 5 KB
    float*    c1          = (float*)(ws + 24576);           // 64 B
    int*      degi        = (int*)(ws + (1 << 20));         // 400 KB
    int*      offs        = (int*)(ws + (2 << 20));         // 400 KB
    float*    dis         = (float*)(ws + (3 << 20));       // 400 KB
    unsigned* binned      = (unsigned*)(ws + (4 << 20));    // 6.4 MB
    int*      csr         = (int*)(ws + (12 << 20));        // 6.4 MB
    float*    g1p         = (float*)(ws + (20 << 20));      // 6.4 MB
    float*    h2p         = (float*)(ws + (28 << 20));      // 6.4 MB

    hipMemsetAsync(bucketCount, 0, NB * sizeof(int), stream);

    k_hist<<<NBLK_BIN, 256, 0, stream>>>(ei + E_EDGES, bucketCount);
    k_scan_buckets<<<1, 512, 0, stream>>>(bucketCount, bucketBase, cursors);
    k_bin<<<NBLK_BIN, 256, 0, stream>>>(ei, cursors, binned);
    k_build<<<NB, 256, 0, stream>>>(binned, bucketBase, degi, offs, dis, csr);

    k_w12<<<1, 256, 0, stream>>>(W1, W2, b1, W12, c1);
    k_g1<<<(N_NODES + 3) / 4, 256, 0, stream>>>(x, dis, W12, g1p);

    k_agg_a<<<(N_NODES + 15) / 16, 256, 0, stream>>>(g1p, csr, offs, degi, c1, h2p);
    k_agg_b<<<(N_NODES + 15) / 16, 256, 0, stream>>>(h2p, csr, offs, degi, b2, out);
}

// Round 6
// 202.748 us; speedup vs baseline: 8.6710x; 1.2675x over previous
//
#include <hip/hip_runtime.h>

#define N_NODES 100000
#define E_EDGES 1600000
#define NCLS 10

#define BW 256                       // bucket width in nodes
#define NB 391                       // ceil(N_NODES / BW)
#define EPB 8192                     // edges per binning block
#define NBLK_BIN 196                 // ceil(E_EDGES / EPB)

// ------- per-block bucket histogram (no global atomics) -------------------
__global__ __launch_bounds__(256) void k_hist(const int* __restrict__ col,
                                              int* __restrict__ blockHist) {
    __shared__ int h[NB];
    int t = threadIdx.x;
    for (int i = t; i < NB; i += 256) h[i] = 0;
    __syncthreads();
    int base = blockIdx.x * EPB;
    int end  = min(base + EPB, E_EDGES);
    for (int e = base + t; e < end; e += 256)
        atomicAdd(&h[col[e] >> 8], 1);
    __syncthreads();
    for (int i = t; i < NB; i += 256)
        blockHist[blockIdx.x * NB + i] = h[i];
}

// ------- deterministic offsets: column scan + bucket-base scan ------------
// blockHist[b][i] <- sum_{b'<b} blockHist[b'][i]  (per-bucket exclusive)
// bucketBase[i]   <- exclusive scan of bucket totals
__global__ __launch_bounds__(512) void k_scan2(int* __restrict__ blockHist,
                                               int* __restrict__ bucketBase) {
    __shared__ int s[512];
    int t = threadIdx.x;
    int run = 0;
    if (t < NB) {
        for (int b = 0; b < NBLK_BIN; ++b) {
            int v = blockHist[b * NB + t];
            blockHist[b * NB + t] = run;
            run += v;
        }
    }
    s[t] = (t < NB) ? run : 0;
    __syncthreads();
    for (int st = 1; st < 512; st <<= 1) {
        int tmp = (t >= st) ? s[t - st] : 0;
        __syncthreads();
        s[t] += tmp;
        __syncthreads();
    }
    if (t < NB) bucketBase[t] = s[t] - run;   // exclusive
    if (t == NB - 1) bucketBase[NB] = s[t];   // = E_EDGES
}

// ------- bin edges into bucketed packed array (deterministic chunks) ------
__global__ __launch_bounds__(256) void k_bin(const int* __restrict__ ei,
                                             const int* __restrict__ blockHist,
                                             const int* __restrict__ bucketBase,
                                             unsigned* __restrict__ binned) {
    __shared__ int h[NB];
    __shared__ int chunk[NB];
    int t = threadIdx.x;
    for (int i = t; i < NB; i += 256) {
        h[i] = 0;
        chunk[i] = bucketBase[i] + blockHist[blockIdx.x * NB + i];
    }
    __syncthreads();
    int base = blockIdx.x * EPB;
    int end  = min(base + EPB, E_EDGES);
    const int* col = ei + E_EDGES;
    for (int e = base + t; e < end; e += 256) {
        int c = col[e];
        int r = ei[e];
        int k = c >> 8;
        int slot = chunk[k] + atomicAdd(&h[k], 1);   // LDS-local rank only
        binned[slot] = ((unsigned)r << 8) | (unsigned)(c & 255);
    }
}

// ---------------- per-bucket: degrees, offs, dis, csr fill ----------------
__global__ __launch_bounds__(256) void k_build(const unsigned* __restrict__ binned,
                                               const int* __restrict__ bucketBase,
                                               int* __restrict__ degi,
                                               int* __restrict__ offs,
                                               float* __restrict__ dis,
                                               int* __restrict__ csr) {
    __shared__ int cnt[BW];
    __shared__ int sc[BW];
    __shared__ int eoff[BW];
    __shared__ int cur[BW];
    int k = blockIdx.x;
    int t = threadIdx.x;
    cnt[t] = 0;
    __syncthreads();
    int s0 = bucketBase[k], s1 = bucketBase[k + 1];
    for (int i = s0 + t; i < s1; i += 256)
        atomicAdd(&cnt[binned[i] & 255], 1);
    __syncthreads();
    int v = cnt[t];
    sc[t] = v;
    __syncthreads();
    for (int st = 1; st < 256; st <<= 1) {
        int tmp = (t >= st) ? sc[t - st] : 0;
        __syncthreads();
        sc[t] += tmp;
        __syncthreads();
    }
    eoff[t] = sc[t] - v;   // exclusive
    cur[t] = 0;
    int node = k * BW + t;
    if (node < N_NODES) {
        degi[node] = v;
        offs[node] = s0 + eoff[t];
        dis[node]  = rsqrtf((float)(v + 1));
    }
    __syncthreads();
    for (int i = s0 + t; i < s1; i += 256) {
        unsigned p = binned[i];
        int lc = p & 255;
        int r  = p >> 8;
        int pos = s0 + eoff[lc] + atomicAdd(&cur[lc], 1);
        csr[pos] = r;
    }
}

// ---------------- W12 = W2 @ W1 ([10,128]), c1 = W2 @ b1 ----------------
__global__ __launch_bounds__(256) void k_w12(const float* __restrict__ W1,
                                             const float* __restrict__ W2,
                                             const float* __restrict__ b1,
                                             float* __restrict__ W12,
                                             float* __restrict__ c1) {
    __shared__ float w1s[128][128];
    int t = threadIdx.x;
    for (int i = t; i < 4096; i += 256) {
        float4 v = ((const float4*)W1)[i];
        int m = i >> 5;
        int kk = (i & 31) << 2;
        *(float4*)&w1s[m][kk] = v;
    }
    __syncthreads();

    int j0 = t >> 7;
    int kk = t & 127;
    #pragma unroll
    for (int i = 0; i < 5; ++i) {
        int j = j0 * 5 + i;
        float acc = 0.f;
        for (int m = 0; m < 128; ++m)
            acc += W2[j * 128 + m] * w1s[m][kk];
        W12[j * 128 + kk] = acc;
    }
    if (t < 16) {
        float acc = 0.f;
        if (t < NCLS)
            for (int m = 0; m < 128; ++m) acc += W2[t * 128 + m] * b1[m];
        c1[t] = (t < NCLS) ? acc : 0.f;
    }
}

// ------- g1 = x @ W12^T, padded [N][16], dis in slot 10 -------------------
// thread-per-row: 32 float4 streaming loads, W12 via wave-uniform s_load.
__global__ __launch_bounds__(64) void k_g1(const float* __restrict__ x,
                                           const float* __restrict__ dis,
                                           const float* __restrict__ W12,
                                           float* __restrict__ g1p) {
    int row = blockIdx.x * 64 + threadIdx.x;
    if (row >= N_NODES) return;

    const float4* x4 = (const float4*)x;
    float acc[NCLS];
    #pragma unroll
    for (int j = 0; j < NCLS; ++j) acc[j] = 0.f;

    #pragma unroll
    for (int k4 = 0; k4 < 32; ++k4) {
        float4 xv = x4[row * 32 + k4];
        #pragma unroll
        for (int j = 0; j < NCLS; ++j) {
            const float* wj = &W12[j * 128 + k4 * 4];   // uniform addr -> s_load
            acc[j] += xv.x * wj[0] + xv.y * wj[1] + xv.z * wj[2] + xv.w * wj[3];
        }
    }

    float o[16];
    #pragma unroll
    for (int j = 0; j < NCLS; ++j) o[j] = acc[j];
    o[10] = dis[row];
    o[11] = 0.f; o[12] = 0.f; o[13] = 0.f; o[14] = 0.f; o[15] = 0.f;
    float4* dst = (float4*)&g1p[row * 16];
    dst[0] = *(const float4*)&o[0];
    dst[1] = *(const float4*)&o[4];
    dst[2] = *(const float4*)&o[8];
    dst[3] = *(const float4*)&o[12];
}

// ------- agg A: h2p = S*g1 + c1 (padded rows, dis in slot 10) -------------
__global__ __launch_bounds__(256) void k_agg_a(const float* __restrict__ g1p,
                                               const int* __restrict__ csr,
                                               const int* __restrict__ offs,
                                               const int* __restrict__ degi,
                                               const float* __restrict__ c1,
                                               float* __restrict__ h2p) {
    int c    = blockIdx.x * 16 + (threadIdx.x >> 4);
    int lane = threadIdx.x & 15;
    if (c >= N_NODES) return;

    float vs = g1p[c * 16 + lane];
    float dc = __shfl(vs, 10, 16);
    float acc = dc * vs;

    int start = offs[c];
    int deg   = degi[c];
    for (int k = 0; k < deg; ++k) {
        int r = csr[start + k];
        float vr = g1p[r * 16 + lane];
        acc += __shfl(vr, 10, 16) * vr;
    }
    float o = (lane < NCLS) ? dc * acc + c1[lane] : (lane == 10 ? dc : 0.f);
    h2p[c * 16 + lane] = o;
}

// ------- agg B: out = S*h2 + b2 (compact N x 10 output) -------------------
__global__ __launch_bounds__(256) void k_agg_b(const float* __restrict__ h2p,
                                               const int* __restrict__ csr,
                                               const int* __restrict__ offs,
                                               const int* __restrict__ degi,
                                               const float* __restrict__ b2,
                                               float* __restrict__ out) {
    int c    = blockIdx.x * 16 + (threadIdx.x >> 4);
    int lane = threadIdx.x & 15;
    if (c >= N_NODES) return;

    float vs = h2p[c * 16 + lane];
    float dc = __shfl(vs, 10, 16);
    float acc = dc * vs;

    int start = offs[c];
    int deg   = degi[c];
    for (int k = 0; k < deg; ++k) {
        int r = csr[start + k];
        float vr = h2p[r * 16 + lane];
        acc += __shfl(vr, 10, 16) * vr;
    }
    if (lane < NCLS) out[c * NCLS + lane] = b2[lane] + dc * acc;
}

extern "C" void kernel_launch(void* const* d_in, const int* in_sizes, int n_in,
                              void* d_out, int out_size, void* d_ws, size_t ws_size,
                              hipStream_t stream) {
    const float* x  = (const float*)d_in[0];
    const int*   ei = (const int*)d_in[1];   // [2, E] int32
    const float* W1 = (const float*)d_in[2];
    const float* b1 = (const float*)d_in[3];
    const float* W2 = (const float*)d_in[4];
    const float* b2 = (const float*)d_in[5];
    float* out = (float*)d_out;

    char* ws = (char*)d_ws;
    int*      bucketBase = (int*)(ws + 0);                  // NB+1 ints
    float*    W12        = (float*)(ws + 4096);             // 5 KB
    float*    c1         = (float*)(ws + 16384);            // 64 B
    int*      blockHist  = (int*)(ws + 32768);              // 196*391 ints ~300 KB
    int*      degi       = (int*)(ws + (1 << 20));          // 400 KB
    int*      offs       = (int*)(ws + (2 << 20));          // 400 KB
    float*    dis        = (float*)(ws + (3 << 20));        // 400 KB
    unsigned* binned     = (unsigned*)(ws + (4 << 20));     // 6.4 MB
    int*      csr        = (int*)(ws + (12 << 20));         // 6.4 MB
    float*    g1p        = (float*)(ws + (20 << 20));       // 6.4 MB
    float*    h2p        = (float*)(ws + (28 << 20));       // 6.4 MB

    k_hist<<<NBLK_BIN, 256, 0, stream>>>(ei + E_EDGES, blockHist);
    k_scan2<<<1, 512, 0, stream>>>(blockHist, bucketBase);
    k_bin<<<NBLK_BIN, 256, 0, stream>>>(ei, blockHist, bucketBase, binned);
    k_build<<<NB, 256, 0, stream>>>(binned, bucketBase, degi, offs, dis, csr);

    k_w12<<<1, 256, 0, stream>>>(W1, W2, b1, W12, c1);
    k_g1<<<(N_NODES + 63) / 64, 64, 0, stream>>>(x, dis, W12, g1p);

    k_agg_a<<<(N_NODES + 15) / 16, 256, 0, stream>>>(g1p, csr, offs, degi, c1, h2p);
    k_agg_b<<<(N_NODES + 15) / 16, 256, 0, stream>>>(h2p, csr, offs, degi, b2, out);
}

// Round 7
// 150.013 us; speedup vs baseline: 11.7192x; 1.3515x over previous
//
#include <hip/hip_runtime.h>

#define N_NODES 100000
#define E_EDGES 1600000
#define NCLS 10

#define BW 256                       // bucket width in nodes
#define NB 391                       // ceil(N_NODES / BW)
#define EPB 8192                     // edges per binning block
#define NBLK_BIN 196                 // ceil(E_EDGES / EPB)

// ------- per-block bucket histogram (no global atomics) -------------------
__global__ __launch_bounds__(256) void k_hist(const int* __restrict__ col,
                                              int* __restrict__ blockHist) {
    __shared__ int h[NB];
    int t = threadIdx.x;
    for (int i = t; i < NB; i += 256) h[i] = 0;
    __syncthreads();
    int base = blockIdx.x * EPB;
    int end  = min(base + EPB, E_EDGES);
    for (int e = base + t; e < end; e += 256)
        atomicAdd(&h[col[e] >> 8], 1);
    __syncthreads();
    for (int i = t; i < NB; i += 256)
        blockHist[blockIdx.x * NB + i] = h[i];
}

// ------- deterministic offsets: column scan + bucket-base scan ------------
__global__ __launch_bounds__(512) void k_scan2(int* __restrict__ blockHist,
                                               int* __restrict__ bucketBase) {
    __shared__ int s[512];
    int t = threadIdx.x;
    int run = 0;
    if (t < NB) {
        for (int b = 0; b < NBLK_BIN; ++b) {
            int v = blockHist[b * NB + t];
            blockHist[b * NB + t] = run;
            run += v;
        }
    }
    s[t] = (t < NB) ? run : 0;
    __syncthreads();
    for (int st = 1; st < 512; st <<= 1) {
        int tmp = (t >= st) ? s[t - st] : 0;
        __syncthreads();
        s[t] += tmp;
        __syncthreads();
    }
    if (t < NB) bucketBase[t] = s[t] - run;   // exclusive
    if (t == NB - 1) bucketBase[NB] = s[t];   // = E_EDGES
}

// ------- bin edges into bucketed packed array (deterministic chunks) ------
__global__ __launch_bounds__(256) void k_bin(const int* __restrict__ ei,
                                             const int* __restrict__ blockHist,
                                             const int* __restrict__ bucketBase,
                                             unsigned* __restrict__ binned) {
    __shared__ int h[NB];
    __shared__ int chunk[NB];
    int t = threadIdx.x;
    for (int i = t; i < NB; i += 256) {
        h[i] = 0;
        chunk[i] = bucketBase[i] + blockHist[blockIdx.x * NB + i];
    }
    __syncthreads();
    int base = blockIdx.x * EPB;
    int end  = min(base + EPB, E_EDGES);
    const int* col = ei + E_EDGES;
    for (int e = base + t; e < end; e += 256) {
        int c = col[e];
        int r = ei[e];
        int k = c >> 8;
        int slot = chunk[k] + atomicAdd(&h[k], 1);   // LDS-local rank only
        binned[slot] = ((unsigned)r << 8) | (unsigned)(c & 255);
    }
}

// ---------------- per-bucket: degrees, offs, dis, csr fill ----------------
__global__ __launch_bounds__(256) void k_build(const unsigned* __restrict__ binned,
                                               const int* __restrict__ bucketBase,
                                               int* __restrict__ degi,
                                               int* __restrict__ offs,
                                               float* __restrict__ dis,
                                               int* __restrict__ csr) {
    __shared__ int cnt[BW];
    __shared__ int sc[BW];
    __shared__ int eoff[BW];
    __shared__ int cur[BW];
    int k = blockIdx.x;
    int t = threadIdx.x;
    cnt[t] = 0;
    __syncthreads();
    int s0 = bucketBase[k], s1 = bucketBase[k + 1];
    for (int i = s0 + t; i < s1; i += 256)
        atomicAdd(&cnt[binned[i] & 255], 1);
    __syncthreads();
    int v = cnt[t];
    sc[t] = v;
    __syncthreads();
    for (int st = 1; st < 256; st <<= 1) {
        int tmp = (t >= st) ? sc[t - st] : 0;
        __syncthreads();
        sc[t] += tmp;
        __syncthreads();
    }
    eoff[t] = sc[t] - v;   // exclusive
    cur[t] = 0;
    int node = k * BW + t;
    if (node < N_NODES) {
        degi[node] = v;
        offs[node] = s0 + eoff[t];
        dis[node]  = rsqrtf((float)(v + 1));
    }
    __syncthreads();
    for (int i = s0 + t; i < s1; i += 256) {
        unsigned p = binned[i];
        int lc = p & 255;
        int r  = p >> 8;
        int pos = s0 + eoff[lc] + atomicAdd(&cur[lc], 1);
        csr[pos] = r;
    }
}

// ---------------- W12 = W2 @ W1 ([10,128]), c1 = W2 @ b1 ----------------
__global__ __launch_bounds__(256) void k_w12(const float* __restrict__ W1,
                                             const float* __restrict__ W2,
                                             const float* __restrict__ b1,
                                             float* __restrict__ W12,
                                             float* __restrict__ c1) {
    __shared__ float w1s[128][128];
    int t = threadIdx.x;
    for (int i = t; i < 4096; i += 256) {
        float4 v = ((const float4*)W1)[i];
        int m = i >> 5;
        int kk = (i & 31) << 2;
        *(float4*)&w1s[m][kk] = v;
    }
    __syncthreads();

    int j0 = t >> 7;
    int kk = t & 127;
    #pragma unroll
    for (int i = 0; i < 5; ++i) {
        int j = j0 * 5 + i;
        float acc = 0.f;
        for (int m = 0; m < 128; ++m)
            acc += W2[j * 128 + m] * w1s[m][kk];
        W12[j * 128 + kk] = acc;
    }
    if (t < 16) {
        float acc = 0.f;
        if (t < NCLS)
            for (int m = 0; m < 128; ++m) acc += W2[t * 128 + m] * b1[m];
        c1[t] = (t < NCLS) ? acc : 0.f;
    }
}

// ------- g1s = dis .* (x @ W12^T), padded [N][16], dis in slot 10 ---------
// thread-per-row: 32 float4 streaming loads, W12 via wave-uniform s_load.
__global__ __launch_bounds__(64) void k_g1(const float* __restrict__ x,
                                           const float* __restrict__ dis,
                                           const float* __restrict__ W12,
                                           float* __restrict__ g1p) {
    int row = blockIdx.x * 64 + threadIdx.x;
    if (row >= N_NODES) return;

    const float4* x4 = (const float4*)x;
    float acc[NCLS];
    #pragma unroll
    for (int j = 0; j < NCLS; ++j) acc[j] = 0.f;

    #pragma unroll
    for (int k4 = 0; k4 < 32; ++k4) {
        float4 xv = x4[row * 32 + k4];
        #pragma unroll
        for (int j = 0; j < NCLS; ++j) {
            const float* wj = &W12[j * 128 + k4 * 4];   // uniform addr -> s_load
            acc[j] += xv.x * wj[0] + xv.y * wj[1] + xv.z * wj[2] + xv.w * wj[3];
        }
    }

    float d = dis[row];
    float o[16];
    #pragma unroll
    for (int j = 0; j < NCLS; ++j) o[j] = d * acc[j];   // pre-scaled row
    o[10] = d;
    o[11] = 0.f; o[12] = 0.f; o[13] = 0.f; o[14] = 0.f; o[15] = 0.f;
    float4* dst = (float4*)&g1p[row * 16];
    dst[0] = *(const float4*)&o[0];
    dst[1] = *(const float4*)&o[4];
    dst[2] = *(const float4*)&o[8];
    dst[3] = *(const float4*)&o[12];
}

// ------- agg A: h2s = dc*(dc*acc + c1), acc = sum of pre-scaled rows ------
__global__ __launch_bounds__(256) void k_agg_a(const float* __restrict__ g1p,
                                               const int* __restrict__ csr,
                                               const int* __restrict__ offs,
                                               const int* __restrict__ degi,
                                               const float* __restrict__ c1,
                                               float* __restrict__ h2p) {
    int c    = blockIdx.x * 16 + (threadIdx.x >> 4);
    int lane = threadIdx.x & 15;
    if (c >= N_NODES) return;

    float vs = g1p[c * 16 + lane];      // pre-scaled self row; slot10 = dc
    float dc = __shfl(vs, 10, 16);
    float acc = vs;                      // self term

    int start = offs[c];
    int deg   = degi[c];
    int k = 0;
    for (; k + 4 <= deg; k += 4) {       // 4 independent gathers in flight
        int r0 = csr[start + k + 0];
        int r1 = csr[start + k + 1];
        int r2 = csr[start + k + 2];
        int r3 = csr[start + k + 3];
        float a0 = g1p[r0 * 16 + lane];
        float a1 = g1p[r1 * 16 + lane];
        float a2 = g1p[r2 * 16 + lane];
        float a3 = g1p[r3 * 16 + lane];
        acc += a0 + a1 + a2 + a3;
    }
    for (; k < deg; ++k)
        acc += g1p[csr[start + k] * 16 + lane];

    float o = dc * (dc * acc + c1[lane]);   // lanes 11-15: acc=0,c1=0 -> 0
    if (lane == 10) o = dc;
    h2p[c * 16 + lane] = o;
}

// ------- agg B: out = dc*acc + b2 ------------------------------------------
__global__ __launch_bounds__(256) void k_agg_b(const float* __restrict__ h2p,
                                               const int* __restrict__ csr,
                                               const int* __restrict__ offs,
                                               const int* __restrict__ degi,
                                               const float* __restrict__ b2,
                                               float* __restrict__ out) {
    int c    = blockIdx.x * 16 + (threadIdx.x >> 4);
    int lane = threadIdx.x & 15;
    if (c >= N_NODES) return;

    float vs = h2p[c * 16 + lane];      // pre-scaled self row; slot10 = dc
    float dc = __shfl(vs, 10, 16);
    float acc = vs;

    int start = offs[c];
    int deg   = degi[c];
    int k = 0;
    for (; k + 4 <= deg; k += 4) {
        int r0 = csr[start + k + 0];
        int r1 = csr[start + k + 1];
        int r2 = csr[start + k + 2];
        int r3 = csr[start + k + 3];
        float a0 = h2p[r0 * 16 + lane];
        float a1 = h2p[r1 * 16 + lane];
        float a2 = h2p[r2 * 16 + lane];
        float a3 = h2p[r3 * 16 + lane];
        acc += a0 + a1 + a2 + a3;
    }
    for (; k < deg; ++k)
        acc += h2p[csr[start + k] * 16 + lane];

    if (lane < NCLS) out[c * NCLS + lane] = dc * acc + b2[lane];
}

extern "C" void kernel_launch(void* const* d_in, const int* in_sizes, int n_in,
                              void* d_out, int out_size, void* d_ws, size_t ws_size,
                              hipStream_t stream) {
    const float* x  = (const float*)d_in[0];
    const int*   ei = (const int*)d_in[1];   // [2, E] int32
    const float* W1 = (const float*)d_in[2];
    const float* b1 = (const float*)d_in[3];
    const float* W2 = (const float*)d_in[4];
    const float* b2 = (const float*)d_in[5];
    float* out = (float*)d_out;

    char* ws = (char*)d_ws;
    int*      bucketBase = (int*)(ws + 0);                  // NB+1 ints
    float*    W12        = (float*)(ws + 4096);             // 5 KB
    float*    c1         = (float*)(ws + 16384);            // 64 B
    int*      blockHist  = (int*)(ws + 32768);              // 196*391 ints ~300 KB
    int*      degi       = (int*)(ws + (1 << 20));          // 400 KB
    int*      offs       = (int*)(ws + (2 << 20));          // 400 KB
    float*    dis        = (float*)(ws + (3 << 20));        // 400 KB
    unsigned* binned     = (unsigned*)(ws + (4 << 20));     // 6.4 MB
    int*      csr        = (int*)(ws + (12 << 20));         // 6.4 MB
    float*    g1p        = (float*)(ws + (20 << 20));       // 6.4 MB
    float*    h2p        = (float*)(ws + (28 << 20));       // 6.4 MB

    k_hist<<<NBLK_BIN, 256, 0, stream>>>(ei + E_EDGES, blockHist);
    k_scan2<<<1, 512, 0, stream>>>(blockHist, bucketBase);
    k_bin<<<NBLK_BIN, 256, 0, stream>>>(ei, blockHist, bucketBase, binned);
    k_build<<<NB, 256, 0, stream>>>(binned, bucketBase, degi, offs, dis, csr);

    k_w12<<<1, 256, 0, stream>>>(W1, W2, b1, W12, c1);
    k_g1<<<(N_NODES + 63) / 64, 64, 0, stream>>>(x, dis, W12, g1p);

    k_agg_a<<<(N_NODES + 15) / 16, 256, 0, stream>>>(g1p, csr, offs, degi, c1, h2p);
    k_agg_b<<<(N_NODES + 15) / 16, 256, 0, stream>>>(h2p, csr, offs, degi, b2, out);
}

// Round 8
// 131.351 us; speedup vs baseline: 13.3842x; 1.1421x over previous
//
#include <hip/hip_runtime.h>
#include <hip/hip_fp16.h>

#define N_NODES 100000
#define E_EDGES 1600000
#define NCLS 10

#define BW 256                       // bucket width in nodes
#define NB 391                       // ceil(N_NODES / BW)
#define EPB 8192                     // edges per binning block
#define NBLK_BIN 196                 // ceil(E_EDGES / EPB)

// ------- per-block bucket histogram (no global atomics) -------------------
__global__ __launch_bounds__(256) void k_hist(const int* __restrict__ col,
                                              int* __restrict__ blockHist) {
    __shared__ int h[NB];
    int t = threadIdx.x;
    for (int i = t; i < NB; i += 256) h[i] = 0;
    __syncthreads();
    int base = blockIdx.x * EPB;
    int end  = min(base + EPB, E_EDGES);
    for (int e = base + t; e < end; e += 256)
        atomicAdd(&h[col[e] >> 8], 1);
    __syncthreads();
    for (int i = t; i < NB; i += 256)
        blockHist[blockIdx.x * NB + i] = h[i];
}

// ------- deterministic offsets: column scan + bucket-base scan ------------
__global__ __launch_bounds__(512) void k_scan2(int* __restrict__ blockHist,
                                               int* __restrict__ bucketBase) {
    __shared__ int s[512];
    int t = threadIdx.x;
    int run = 0;
    if (t < NB) {
        for (int b = 0; b < NBLK_BIN; ++b) {
            int v = blockHist[b * NB + t];
            blockHist[b * NB + t] = run;
            run += v;
        }
    }
    s[t] = (t < NB) ? run : 0;
    __syncthreads();
    for (int st = 1; st < 512; st <<= 1) {
        int tmp = (t >= st) ? s[t - st] : 0;
        __syncthreads();
        s[t] += tmp;
        __syncthreads();
    }
    if (t < NB) bucketBase[t] = s[t] - run;   // exclusive
    if (t == NB - 1) bucketBase[NB] = s[t];   // = E_EDGES
}

// ------- bin edges into bucketed packed array (deterministic chunks) ------
__global__ __launch_bounds__(256) void k_bin(const int* __restrict__ ei,
                                             const int* __restrict__ blockHist,
                                             const int* __restrict__ bucketBase,
                                             unsigned* __restrict__ binned) {
    __shared__ int h[NB];
    __shared__ int chunk[NB];
    int t = threadIdx.x;
    for (int i = t; i < NB; i += 256) {
        h[i] = 0;
        chunk[i] = bucketBase[i] + blockHist[blockIdx.x * NB + i];
    }
    __syncthreads();
    int base = blockIdx.x * EPB;
    int end  = min(base + EPB, E_EDGES);
    const int* col = ei + E_EDGES;
    for (int e = base + t; e < end; e += 256) {
        int c = col[e];
        int r = ei[e];
        int k = c >> 8;
        int slot = chunk[k] + atomicAdd(&h[k], 1);   // LDS-local rank only
        binned[slot] = ((unsigned)r << 8) | (unsigned)(c & 255);
    }
}

// ---------------- per-bucket: degrees, offs, dis, csr fill ----------------
__global__ __launch_bounds__(256) void k_build(const unsigned* __restrict__ binned,
                                               const int* __restrict__ bucketBase,
                                               int* __restrict__ degi,
                                               int* __restrict__ offs,
                                               float* __restrict__ dis,
                                               int* __restrict__ csr) {
    __shared__ int cnt[BW];
    __shared__ int sc[BW];
    __shared__ int eoff[BW];
    __shared__ int cur[BW];
    int k = blockIdx.x;
    int t = threadIdx.x;
    cnt[t] = 0;
    __syncthreads();
    int s0 = bucketBase[k], s1 = bucketBase[k + 1];
    for (int i = s0 + t; i < s1; i += 256)
        atomicAdd(&cnt[binned[i] & 255], 1);
    __syncthreads();
    int v = cnt[t];
    sc[t] = v;
    __syncthreads();
    for (int st = 1; st < 256; st <<= 1) {
        int tmp = (t >= st) ? sc[t - st] : 0;
        __syncthreads();
        sc[t] += tmp;
        __syncthreads();
    }
    eoff[t] = sc[t] - v;   // exclusive
    cur[t] = 0;
    int node = k * BW + t;
    if (node < N_NODES) {
        degi[node] = v;
        offs[node] = s0 + eoff[t];
        dis[node]  = rsqrtf((float)(v + 1));
    }
    __syncthreads();
    for (int i = s0 + t; i < s1; i += 256) {
        unsigned p = binned[i];
        int lc = p & 255;
        int r  = p >> 8;
        int pos = s0 + eoff[lc] + atomicAdd(&cur[lc], 1);
        csr[pos] = r;
    }
}

// ---------------- W12 = W2 @ W1 ([10,128]), c1 = W2 @ b1 (16 padded) ------
__global__ __launch_bounds__(256) void k_w12(const float* __restrict__ W1,
                                             const float* __restrict__ W2,
                                             const float* __restrict__ b1,
                                             float* __restrict__ W12,
                                             float* __restrict__ c1) {
    __shared__ float w1s[128][128];
    int t = threadIdx.x;
    for (int i = t; i < 4096; i += 256) {
        float4 v = ((const float4*)W1)[i];
        int m = i >> 5;
        int kk = (i & 31) << 2;
        *(float4*)&w1s[m][kk] = v;
    }
    __syncthreads();

    int j0 = t >> 7;
    int kk = t & 127;
    #pragma unroll
    for (int i = 0; i < 5; ++i) {
        int j = j0 * 5 + i;
        float acc = 0.f;
        for (int m = 0; m < 128; ++m)
            acc += W2[j * 128 + m] * w1s[m][kk];
        W12[j * 128 + kk] = acc;
    }
    if (t < 16) {
        float acc = 0.f;
        if (t < NCLS)
            for (int m = 0; m < 128; ++m) acc += W2[t * 128 + m] * b1[m];
        c1[t] = (t < NCLS) ? acc : 0.f;
    }
}

// ------- g1h = fp16( dis .* (x @ W12^T) ), rows of 16 halfs (32B) ---------
// thread-per-row: 32 float4 streaming loads, W12 via wave-uniform s_load.
__global__ __launch_bounds__(64) void k_g1(const float* __restrict__ x,
                                           const float* __restrict__ dis,
                                           const float* __restrict__ W12,
                                           __half2* __restrict__ g1h) {
    int row = blockIdx.x * 64 + threadIdx.x;
    if (row >= N_NODES) return;

    const float4* x4 = (const float4*)x;
    float acc[NCLS];
    #pragma unroll
    for (int j = 0; j < NCLS; ++j) acc[j] = 0.f;

    #pragma unroll
    for (int k4 = 0; k4 < 32; ++k4) {
        float4 xv = x4[row * 32 + k4];
        #pragma unroll
        for (int j = 0; j < NCLS; ++j) {
            const float* wj = &W12[j * 128 + k4 * 4];   // uniform addr -> s_load
            acc[j] += xv.x * wj[0] + xv.y * wj[1] + xv.z * wj[2] + xv.w * wj[3];
        }
    }

    float d = dis[row];
    __half2 hp[8];
    #pragma unroll
    for (int j = 0; j < 5; ++j)
        hp[j] = __floats2half2_rn(d * acc[2 * j], d * acc[2 * j + 1]);
    hp[5] = __floats2half2_rn(0.f, 0.f);
    hp[6] = hp[5];
    hp[7] = hp[5];
    uint4* dst = (uint4*)&g1h[row * 8];
    dst[0] = *(const uint4*)&hp[0];
    dst[1] = *(const uint4*)&hp[4];
}

// ------- agg A: h2h = fp16( dc*(dc*acc + c1) ), acc = sum of scaled rows --
// 8-lane groups; lane j covers feats {2j, 2j+1}; f32 accumulation.
__global__ __launch_bounds__(256) void k_agg_a(const __half2* __restrict__ g1h,
                                               const float* __restrict__ dis,
                                               const int* __restrict__ csr,
                                               const int* __restrict__ offs,
                                               const int* __restrict__ degi,
                                               const float* __restrict__ c1,
                                               __half2* __restrict__ h2h) {
    int c = blockIdx.x * 32 + (threadIdx.x >> 3);
    int j = threadIdx.x & 7;
    if (c >= N_NODES) return;

    float2 acc = __half22float2(g1h[c * 8 + j]);   // self (pre-scaled)

    int start = offs[c];
    int deg   = degi[c];
    int k = 0;
    for (; k + 4 <= deg; k += 4) {
        int r0 = csr[start + k + 0];
        int r1 = csr[start + k + 1];
        int r2 = csr[start + k + 2];
        int r3 = csr[start + k + 3];
        float2 a0 = __half22float2(g1h[r0 * 8 + j]);
        float2 a1 = __half22float2(g1h[r1 * 8 + j]);
        float2 a2 = __half22float2(g1h[r2 * 8 + j]);
        float2 a3 = __half22float2(g1h[r3 * 8 + j]);
        acc.x += (a0.x + a1.x) + (a2.x + a3.x);
        acc.y += (a0.y + a1.y) + (a2.y + a3.y);
    }
    for (; k < deg; ++k) {
        float2 a = __half22float2(g1h[csr[start + k] * 8 + j]);
        acc.x += a.x;
        acc.y += a.y;
    }

    float dc = dis[c];
    float ox = dc * (dc * acc.x + c1[2 * j]);       // j>=5: acc=0,c1=0 -> 0
    float oy = dc * (dc * acc.y + c1[2 * j + 1]);
    h2h[c * 8 + j] = __floats2half2_rn(ox, oy);
}

// ------- agg B: out = dc*acc + b2 (compact N x 10 f32 output) -------------
__global__ __launch_bounds__(256) void k_agg_b(const __half2* __restrict__ h2h,
                                               const float* __restrict__ dis,
                                               const int* __restrict__ csr,
                                               const int* __restrict__ offs,
                                               const int* __restrict__ degi,
                                               const float* __restrict__ b2,
                                               float* __restrict__ out) {
    int c = blockIdx.x * 32 + (threadIdx.x >> 3);
    int j = threadIdx.x & 7;
    if (c >= N_NODES) return;

    float2 acc = __half22float2(h2h[c * 8 + j]);   // self (pre-scaled)

    int start = offs[c];
    int deg   = degi[c];
    int k = 0;
    for (; k + 4 <= deg; k += 4) {
        int r0 = csr[start + k + 0];
        int r1 = csr[start + k + 1];
        int r2 = csr[start + k + 2];
        int r3 = csr[start + k + 3];
        float2 a0 = __half22float2(h2h[r0 * 8 + j]);
        float2 a1 = __half22float2(h2h[r1 * 8 + j]);
        float2 a2 = __half22float2(h2h[r2 * 8 + j]);
        float2 a3 = __half22float2(h2h[r3 * 8 + j]);
        acc.x += (a0.x + a1.x) + (a2.x + a3.x);
        acc.y += (a0.y + a1.y) + (a2.y + a3.y);
    }
    for (; k < deg; ++k) {
        float2 a = __half22float2(h2h[csr[start + k] * 8 + j]);
        acc.x += a.x;
        acc.y += a.y;
    }

    if (j < 5) {
        float dc = dis[c];
        float2 o;
        o.x = dc * acc.x + b2[2 * j];
        o.y = dc * acc.y + b2[2 * j + 1];
        *(float2*)&out[c * NCLS + 2 * j] = o;
    }
}

extern "C" void kernel_launch(void* const* d_in, const int* in_sizes, int n_in,
                              void* d_out, int out_size, void* d_ws, size_t ws_size,
                              hipStream_t stream) {
    const float* x  = (const float*)d_in[0];
    const int*   ei = (const int*)d_in[1];   // [2, E] int32
    const float* W1 = (const float*)d_in[2];
    const float* b1 = (const float*)d_in[3];
    const float* W2 = (const float*)d_in[4];
    const float* b2 = (const float*)d_in[5];
    float* out = (float*)d_out;

    char* ws = (char*)d_ws;
    int*      bucketBase = (int*)(ws + 0);                  // NB+1 ints
    float*    W12        = (float*)(ws + 4096);             // 5 KB
    float*    c1         = (float*)(ws + 16384);            // 64 B (16 padded)
    int*      blockHist  = (int*)(ws + 32768);              // 196*391 ints ~300 KB
    int*      degi       = (int*)(ws + (1 << 20));          // 400 KB
    int*      offs       = (int*)(ws + (2 << 20));          // 400 KB
    float*    dis        = (float*)(ws + (3 << 20));        // 400 KB
    unsigned* binned     = (unsigned*)(ws + (4 << 20));     // 6.4 MB
    int*      csr        = (int*)(ws + (12 << 20));         // 6.4 MB
    __half2*  g1h        = (__half2*)(ws + (20 << 20));     // 3.2 MB
    __half2*  h2h        = (__half2*)(ws + (24 << 20));     // 3.2 MB

    k_hist<<<NBLK_BIN, 256, 0, stream>>>(ei + E_EDGES, blockHist);
    k_scan2<<<1, 512, 0, stream>>>(blockHist, bucketBase);
    k_bin<<<NBLK_BIN, 256, 0, stream>>>(ei, blockHist, bucketBase, binned);
    k_build<<<NB, 256, 0, stream>>>(binned, bucketBase, degi, offs, dis, csr);

    k_w12<<<1, 256, 0, stream>>>(W1, W2, b1, W12, c1);
    k_g1<<<(N_NODES + 63) / 64, 64, 0, stream>>>(x, dis, W12, g1h);

    k_agg_a<<<(N_NODES + 31) / 32, 256, 0, stream>>>(g1h, dis, csr, offs, degi, c1, h2h);
    k_agg_b<<<(N_NODES + 31) / 32, 256, 0, stream>>>(h2h, dis, csr, offs, degi, b2, out);
}